// Round 5
// baseline (2154.957 us; speedup 1.0000x reference)
//
#include <hip/hip_runtime.h>
#include <math.h>

#define H     1536
#define H3    4608
#define V     128
#define ML    128
#define MLP1  129
#define LEN   64
#define NBLK  256
#define NTHR  384          // 6 waves
#define WPB   6
#define NWAVE (NBLK*WPB)   // 1536
#define ACC_N    260       // padded 257 (129 attn + 128 out logits)
#define ACC_ROWS 8
#define ACC_STEP (ACC_ROWS*ACC_N)   // 2080 ull per step
#define TA_STRIDE 132

#define SCALEF     1099511627776.0f            // 2^40
#define INV_SCALED 9.094947017729282379150390625e-13  // 2^-40 (double, exact)

// epoch channels
#define CH_ENC 0
#define CH_EX  1
#define CH_EH  2
#define CH_EA  3
#define NLINE  32          // counter lines per channel (8 blocks each)

// ---- workspace layout (bytes) ----
// write-once-per-address discipline: writers use UC stores / atomics,
// readers use plain cached loads (first touch is post-publish/detect).
#define OFF_BAR 0                         // 4096: setup barrier lines
#define OFF_CNT 4096                      // 8192: 4 ch x 32 lines x 64B epochs
#define OFF_ACC 12288                     // ull[129][8][260] = 2146560
#define MEMSET_BYTES 2158848              // bar + cnt + accseq
#define OFF_HS  2158848                   // float[128][1536] decoder h seq
#define OFF_XS  2945280                   // float[128][1536] decoder x seq
#define OFF_XE  3731712                   // float[64][1536]
#define OFF_GI  4124928                   // float[64][4608]
#define OFF_EO  5304576                   // float[64][1536]
#define OFF_M   5697792                   // float[1536][64]
#define OFF_TA  6091008                   // float[128][132]
#define OFF_TC  6158592                   // float[128][1536]
#define OFF_CT  6945024                   // float[1536][260]
#define WS_END  8542464

// ---- cache-bypassing (device-coherent) accessors ----
__device__ __forceinline__ void uc_stf(float* p, float v){
  __hip_atomic_store(p, v, __ATOMIC_RELAXED, __HIP_MEMORY_SCOPE_AGENT);
}
__device__ __forceinline__ unsigned uc_ldu(const unsigned* p){
  return __hip_atomic_load(p, __ATOMIC_RELAXED, __HIP_MEMORY_SCOPE_AGENT);
}
__device__ __forceinline__ void uc_stu64(unsigned long long* p, unsigned long long v){
  __hip_atomic_store(p, v, __ATOMIC_RELAXED, __HIP_MEMORY_SCOPE_AGENT);
}

// ---- epoch primitives: producer-count, consumer-detect ----------------------
// 32 lines per channel (64B apart); block b bumps line b>>3 (8 blocks/line —
// short same-line RMW queues); consumers use 32 threads, one per line, until
// each line reaches target = 8*epoch.
__device__ __forceinline__ void bump(unsigned* cnt, int ch, int b){
  __hip_atomic_fetch_add(cnt + (ch*NLINE + (b>>3))*16, 1u,
                         __ATOMIC_RELAXED, __HIP_MEMORY_SCOPE_AGENT);
}
__device__ __forceinline__ void waitline(const unsigned* cnt, int ch, int tid,
                                         unsigned target){
  if(tid < NLINE){
    const unsigned* line = cnt + (ch*NLINE + tid)*16;
    while(uc_ldu(line) < target) __builtin_amdgcn_s_sleep(1);
  }
}

__device__ __forceinline__ float wred(float v){
  #pragma unroll
  for(int s=32;s>0;s>>=1) v += __shfl_xor(v, s, 64);
  return v;
}

__device__ __forceinline__ void load6(const float* p, int lane, float4 r[6]){
  const float4* q = (const float4*)p;
  #pragma unroll
  for(int c=0;c<6;c++) r[c] = q[c*64+lane];
}
__device__ __forceinline__ float dot4(const float4 a, const float4 b){
  return a.x*b.x + a.y*b.y + a.z*b.z + a.w*b.w;
}
__device__ __forceinline__ float dot6(const float4 a[6], const float4 b[6]){
  float s=0.f;
  #pragma unroll
  for(int c=0;c<6;c++) s += dot4(a[c], b[c]);
  return s;
}

// ---- monotonic two-level tree barrier (setup phases only, 4 rounds) --------
__device__ __forceinline__ void gbar(unsigned* bar, int rnd){
  __syncthreads();
  if(threadIdx.x==0){
    unsigned* grp  = bar + 32*(1 + (blockIdx.x >> 4));
    unsigned* root = bar;
    unsigned a = __hip_atomic_fetch_add(grp, 1u, __ATOMIC_RELAXED, __HIP_MEMORY_SCOPE_AGENT);
    if((a & 0xFFFFu) == (unsigned)(16*rnd + 15)){
      unsigned ra = __hip_atomic_fetch_add(root, 1u, __ATOMIC_RELAXED, __HIP_MEMORY_SCOPE_AGENT);
      if(ra == (unsigned)(16*rnd + 15)){
        #pragma unroll
        for(int g=0; g<16; g++)
          __hip_atomic_fetch_add(bar + 32*(1+g), 0x10000u,
                                 __ATOMIC_RELAXED, __HIP_MEMORY_SCOPE_AGENT);
      } else {
        while((uc_ldu(grp) >> 16) < (unsigned)(rnd+1))
          __builtin_amdgcn_s_sleep(1);
      }
    } else {
      while((uc_ldu(grp) >> 16) < (unsigned)(rnd+1))
        __builtin_amdgcn_s_sleep(1);
    }
  }
  __syncthreads();
}

__global__ __launch_bounds__(NTHR, 2)
void seq2seq_kernel(const int* __restrict__ toks,
                    const float* __restrict__ emb_enc,
                    const float* __restrict__ enc_Wih,
                    const float* __restrict__ enc_Whh,
                    const float* __restrict__ enc_bih,
                    const float* __restrict__ enc_bhh,
                    const float* __restrict__ emb_dec,
                    const float* __restrict__ attn_W,
                    const float* __restrict__ attn_b,
                    const float* __restrict__ comb_W,
                    const float* __restrict__ comb_b,
                    const float* __restrict__ dec_Wih,
                    const float* __restrict__ dec_Whh,
                    const float* __restrict__ dec_bih,
                    const float* __restrict__ dec_bhh,
                    const float* __restrict__ out_W,
                    const float* __restrict__ out_b,
                    float* __restrict__ out,
                    char* __restrict__ ws)
{
  const int tid = threadIdx.x, b = blockIdx.x;
  const int lane = tid & 63, w = tid >> 6;
  const int gw = b*WPB + w;          // 0..1535
  int rnd = 0;

  unsigned* bar = (unsigned*)ws;
  unsigned* cnt = (unsigned*)(ws + OFF_CNT);
  unsigned long long* accseq = (unsigned long long*)(ws + OFF_ACC);
  float* hseq = (float*)(ws + OFF_HS);
  float* xseq = (float*)(ws + OFF_XS);
  float* Xe = (float*)(ws + OFF_XE);
  float* Gi = (float*)(ws + OFF_GI);
  float* EO = (float*)(ws + OFF_EO);
  float* Mm = (float*)(ws + OFF_M);
  float* tA = (float*)(ws + OFF_TA);
  float* tC = (float*)(ws + OFF_TC);
  float* cT = (float*)(ws + OFF_CT);

  __shared__ float smem[WPB*3*H];    // 110.6 KB: Whh pin / GEMM tiles
  __shared__ float scT[WPB*ACC_N];   // block's 6 cT rows (6.25 KB)
  __shared__ float shc[8];

  // ================= E0: gather encoder inputs X, build colT (UC writes) =====
  for(int idx = b*NTHR + tid; idx < LEN*H; idx += NBLK*NTHR){
    int t = idx / H, k = idx - t*H;
    uc_stf(&Xe[idx], emb_enc[toks[t]*H + k]);
  }
  for(int idx = b*NTHR + tid; idx < H*257; idx += NBLK*NTHR){
    int i = idx / 257, c = idx - i*257;
    float v = (c < MLP1) ? attn_W[(size_t)c*2*H + H + i]
                         : out_W[(size_t)(c-MLP1)*H + i];
    uc_stf(&cT[(size_t)i*ACC_N + c], v);
  }
  gbar(bar, rnd++);

  // ================= E1: Gi = enc_Wih @ X^T + bih (tiled GEMM) ================
  {
    int r = b*18 + w*3;
    for(int g=0; g<4; g++){
      __syncthreads();
      for(int idx = tid; idx < 16*384; idx += NTHR)
        ((float4*)smem)[idx] = ((const float4*)Xe)[g*16*384 + idx];
      __syncthreads();
      float4 rv0[6], rv1[6], rv2[6];
      load6(enc_Wih + (size_t)r*H,     lane, rv0);
      load6(enc_Wih + (size_t)(r+1)*H, lane, rv1);
      load6(enc_Wih + (size_t)(r+2)*H, lane, rv2);
      float a0[16], a1[16], a2[16];
      #pragma unroll
      for(int t2=0;t2<16;t2++){ a0[t2]=0.f; a1[t2]=0.f; a2[t2]=0.f; }
      #pragma unroll
      for(int c=0;c<6;c++){
        #pragma unroll
        for(int t2=0;t2<16;t2++){
          float4 x = ((float4*)smem)[t2*384 + c*64 + lane];
          a0[t2] += dot4(rv0[c], x);
          a1[t2] += dot4(rv1[c], x);
          a2[t2] += dot4(rv2[c], x);
        }
      }
      float bi0 = enc_bih[r], bi1 = enc_bih[r+1], bi2 = enc_bih[r+2];
      #pragma unroll
      for(int t2=0;t2<16;t2++){
        float s0 = wred(a0[t2]), s1 = wred(a1[t2]), s2 = wred(a2[t2]);
        if(lane==0){
          uc_stf(&Gi[(size_t)(g*16+t2)*H3 + r    ], s0 + bi0);
          uc_stf(&Gi[(size_t)(g*16+t2)*H3 + r + 1], s1 + bi1);
          uc_stf(&Gi[(size_t)(g*16+t2)*H3 + r + 2], s2 + bi2);
        }
      }
    }
  }
  gbar(bar, rnd++);

  // ================= TC: tblCT[v][i] = comb_W[i][:H] . emb_dec[v] ============
  {
    int i = gw;
    float4 rv[6]; load6(comb_W + (size_t)i*2*H, lane, rv);
    for(int g=0; g<8; g++){
      __syncthreads();
      for(int idx = tid; idx < 16*384; idx += NTHR)
        ((float4*)smem)[idx] = ((const float4*)emb_dec)[g*16*384 + idx];
      __syncthreads();
      float a0[16];
      #pragma unroll
      for(int t2=0;t2<16;t2++) a0[t2]=0.f;
      #pragma unroll
      for(int c=0;c<6;c++){
        #pragma unroll
        for(int t2=0;t2<16;t2++){
          float4 x = ((float4*)smem)[t2*384 + c*64 + lane];
          a0[t2] += dot4(rv[c], x);
        }
      }
      #pragma unroll
      for(int t2=0;t2<16;t2++){
        float s = wred(a0[t2]);
        if(lane==0) uc_stf(&tC[(size_t)(g*16+t2)*H + i], s);
      }
    }
  }

  // ================= TA: tblAT[v][j] = attn_W[j][:H] . emb_dec[v] ============
  for(int task = gw; task < MLP1*V; task += NWAVE){
    int j = task >> 7, v = task & 127;
    float4 av[6]; load6(attn_W + (size_t)j*2*H, lane, av);
    float4 ev[6]; load6(emb_dec + (size_t)v*H, lane, ev);
    float s = wred(dot6(av, ev));
    if(lane==0) uc_stf(&tA[v*TA_STRIDE + j], s);
  }
  gbar(bar, rnd++);

  // ======= pin enc_Whh rows (i, i+H, i+2H for this block's 6 i's) in LDS =====
  for(int idx = tid; idx < 18*384; idx += NTHR){
    int row = idx/384, k4 = idx - row*384;
    int w2 = row/3, gate = row - w2*3;
    ((float4*)smem)[idx] =
      ((const float4*)enc_Whh)[((size_t)gate*H + b*WPB + w2)*384 + k4];
  }
  // ---- hoist encoder per-step constants into registers ----
  const int i0 = gw;
  float gi0 = Gi[(size_t)lane*H3 + i0];
  float gi1 = Gi[(size_t)lane*H3 + i0 + H];
  float gi2 = Gi[(size_t)lane*H3 + i0 + 2*H];
  float eb0 = enc_bhh[i0], eb1 = enc_bhh[i0+H], eb2 = enc_bhh[i0+2*H];
  __syncthreads();

  // ================= encoder loop: 64 steps, epoch handoff, direct reads =====
  for(int t=0; t<LEN; t++){
    float4 hv[6];
    float hp;
    if(t==0){
      float4 z4 = {0.f,0.f,0.f,0.f};
      #pragma unroll
      for(int c=0;c<6;c++) hv[c] = z4;
      hp = 0.f;
    } else {
      waitline(cnt, CH_ENC, tid, (unsigned)(8*t));
      __syncthreads();
      load6(EO + (size_t)(t-1)*H, lane, hv);
      hp = EO[(size_t)(t-1)*H + i0];
    }
    float s[3];
    #pragma unroll
    for(int g=0; g<3; g++){
      const float4* sr = (const float4*)smem + (w*3+g)*384;
      float t0=0.f;
      #pragma unroll
      for(int c=0;c<6;c++) t0 += dot4(sr[c*64+lane], hv[c]);
      s[g] = wred(t0);
    }
    float ir = __shfl(gi0, t, 64), iz = __shfl(gi1, t, 64), in_ = __shfl(gi2, t, 64);
    if(lane==0){
      float r = 1.f/(1.f+expf(-(ir + s[0] + eb0)));
      float z = 1.f/(1.f+expf(-(iz + s[1] + eb1)));
      float n = tanhf(in_ + r*(s[2] + eb2));
      float hn = (1.f-z)*n + z*hp;
      uc_stf(&EO[(size_t)t*H + i0], hn);
    }
    __syncthreads();           // drains the EO stores of all waves
    if(tid==0) bump(cnt, CH_ENC, b);
  }
  waitline(cnt, CH_ENC, tid, (unsigned)(8*LEN));
  __syncthreads();             // all EO published

  // ================= M[i][j] = comb_W[i][H:] . enc_out[j] (j<64) =============
  {
    int i = gw;
    float4 rv[6]; load6(comb_W + (size_t)i*2*H + H, lane, rv);
    for(int g=0; g<4; g++){
      __syncthreads();
      for(int idx = tid; idx < 16*384; idx += NTHR)
        ((float4*)smem)[idx] = ((const float4*)EO)[g*16*384 + idx];
      __syncthreads();
      float a0[16];
      #pragma unroll
      for(int t2=0;t2<16;t2++) a0[t2]=0.f;
      #pragma unroll
      for(int c=0;c<6;c++){
        #pragma unroll
        for(int t2=0;t2<16;t2++){
          float4 x = ((float4*)smem)[t2*384 + c*64 + lane];
          a0[t2] += dot4(rv[c], x);
        }
      }
      #pragma unroll
      for(int t2=0;t2<16;t2++){
        float s = wred(a0[t2]);
        if(lane==0) uc_stf(&Mm[(size_t)i*64 + g*16 + t2], s);
      }
    }
  }

  // ====== a0: initial attn logits (raw h-part) into accseq[0] row 0 ==========
  if(gw < MLP1){
    int j = gw;
    float4 av[6]; load6(attn_W + (size_t)j*2*H + H, lane, av);
    float4 hv[6]; load6(EO + (size_t)(LEN-1)*H, lane, hv);  // final enc h
    float s = wred(dot6(av, hv));
    if(lane==0)
      uc_stu64(&accseq[j], (unsigned long long)(long long)rintf(s*SCALEF));
  }
  // pin dec_Whh rows in LDS
  for(int idx = tid; idx < 18*384; idx += NTHR){
    int row = idx/384, k4 = idx - row*384;
    int w2 = row/3, gate = row - w2*3;
    ((float4*)smem)[idx] =
      ((const float4*)dec_Whh)[((size_t)gate*H + b*WPB + w2)*384 + k4];
  }
  // block's 6 cT rows into LDS
  for(int idx = tid; idx < WPB*ACC_N; idx += NTHR){
    int w2 = idx / ACC_N, c = idx - w2*ACC_N;
    scT[idx] = cT[(size_t)(b*WPB + w2)*ACC_N + c];
  }
  gbar(bar, rnd++);

  // ---- hoist decoder per-step constants into registers (persistent) ----
  const int i = gw;
  float4 wx0[6], wx1[6], wx2[6];              // 72 VGPRs: this wave's Wx rows
  load6(dec_Wih + (size_t)i*H,         lane, wx0);
  load6(dec_Wih + ((size_t)H + i)*H,   lane, wx1);
  load6(dec_Wih + ((size_t)2*H + i)*H, lane, wx2);
  const float mreg = Mm[(size_t)i*64 + lane]; // Mm row, 1 float/lane
  const float ct0 = tC[(size_t)lane*H + i];   // tC column, 2 floats/lane
  const float ct1 = tC[(size_t)(64+lane)*H + i];
  const float ib0 = dec_bih[i], ib1 = dec_bih[i+H], ib2 = dec_bih[i+2*H];
  const float hb0 = dec_bhh[i], hb1 = dec_bhh[i+H], hb2 = dec_bhh[i+2*H];
  const float cb  = comb_b[i];
  const float ob0 = out_b[lane], ob1 = out_b[64+lane];
  const float ab0 = attn_b[lane], ab1 = attn_b[64+lane], ab2 = attn_b[128];

  // ================= decoder loop: 128 steps, 3 epoch handoffs each ==========
  for(int t=0; t<ML; t++){
    const unsigned long long* accC = accseq + (size_t)t*ACC_STEP;
    unsigned long long* accA = accseq + (size_t)(t+1)*ACC_STEP;

    // ---- wait h(t-1); read directly (no LDS stage) ----
    const float* hprev = (t==0) ? (EO + (size_t)(LEN-1)*H) : (hseq + (size_t)(t-1)*H);
    if(t>0){
      waitline(cnt, CH_EH, tid, (unsigned)(8*t));
      __syncthreads();
    }
    float4 hv[6]; load6(hprev, lane, hv);
    const float hp = hprev[i];

    // ---- Wh . h (only needs h; overlaps producers' atomic drain) ----
    float sWh[3];
    #pragma unroll
    for(int g=0; g<3; g++){
      const float4* sp = (const float4*)smem + (w*3+g)*384;
      float t1=0.f;
      #pragma unroll
      for(int c=0;c<6;c++) t1 += dot4(sp[c*64+lane], hv[c]);
      sWh[g] = wred(t1);
    }

    // ---- wait acc(t) complete ----
    if(t>0) waitline(cnt, CH_EA, tid, (unsigned)(8*t));
    __syncthreads();

    // ---- per-lane direct fixed-point bank sums (no sv LDS, no barrier) ----
    const long long* aC = (const long long*)accC;
    long long s0=0, s1=0, ax0=0, ax1=0;
    #pragma unroll
    for(int r2=0; r2<ACC_ROWS; r2++){
      s0  += aC[r2*ACC_N + MLP1 + lane];
      s1  += aC[r2*ACC_N + MLP1 + 64 + lane];
      ax0 += aC[r2*ACC_N + lane];
      ax1 += aC[r2*ACC_N + 64 + lane];
    }
    long long ax2 = 0;
    if(lane==0){
      #pragma unroll
      for(int r2=0; r2<ACC_ROWS; r2++) ax2 += aC[r2*ACC_N + 128];
    }

    // ---- per-wave register-only argmax over out logits (all waves) ----
    float o0 = (float)((double)s0 * INV_SCALED) + ob0;
    float o1 = (float)((double)s1 * INV_SCALED) + ob1;
    float mv; int mi;
    if(o0 >= o1){ mv=o0; mi=lane; } else { mv=o1; mi=64+lane; }
    #pragma unroll
    for(int sft=32; sft>0; sft>>=1){
      float ov = __shfl_xor(mv, sft, 64);
      int   oi = __shfl_xor(mi, sft, 64);
      if(ov > mv || (ov == mv && oi < mi)){ mv = ov; mi = oi; }
    }
    const int tok = (t==0) ? 0 : mi;

    // ---- per-wave register-only attention softmax ----
    float v0 = (float)((double)ax0 * INV_SCALED) + tA[tok*TA_STRIDE + lane]      + ab0;
    float v1 = (float)((double)ax1 * INV_SCALED) + tA[tok*TA_STRIDE + 64 + lane] + ab1;
    float v2 = (lane==0)
             ? ((float)((double)ax2 * INV_SCALED) + tA[tok*TA_STRIDE + 128] + ab2)
             : -1e30f;
    float m0 = fmaxf(fmaxf(v0, v1), v2);
    #pragma unroll
    for(int sft=32; sft>0; sft>>=1) m0 = fmaxf(m0, __shfl_xor(m0, sft, 64));
    float e0 = expf(v0 - m0);
    float esum = e0 + expf(v1 - m0) + ((lane==0) ? expf(v2 - m0) : 0.f);
    esum = wred(esum);
    const float invd = 1.f/esum;

    // ---- x[i] = relu(tC[tok][i] + (Mm[i,:64].e)*invd + comb_b[i]); publish --
    {
      float s = wred(mreg * e0);
      float ctv = (tok < 64) ? __shfl(ct0, tok, 64) : __shfl(ct1, tok-64, 64);
      if(lane==0)
        uc_stf(&xseq[(size_t)t*H + i], fmaxf(ctv + s*invd + cb, 0.f));
    }
    __syncthreads();           // drain x stores
    if(tid==0) bump(cnt, CH_EX, b);

    // ---- wait x complete; read directly; Wx . x; gates; publish h ----
    waitline(cnt, CH_EX, tid, (unsigned)(8*(t+1)));
    __syncthreads();
    float4 xv[6]; load6(xseq + (size_t)t*H, lane, xv);
    float t0=0.f, t1=0.f, t2=0.f;
    #pragma unroll
    for(int c=0;c<6;c++){
      t0 += dot4(wx0[c], xv[c]);
      t1 += dot4(wx1[c], xv[c]);
      t2 += dot4(wx2[c], xv[c]);
    }
    float sWx0 = wred(t0), sWx1 = wred(t1), sWx2 = wred(t2);
    if(lane==0){
      float r = 1.f/(1.f+expf(-(sWx0+ib0 + sWh[0]+hb0)));
      float z = 1.f/(1.f+expf(-(sWx1+ib1 + sWh[1]+hb1)));
      float n = tanhf(sWx2+ib2 + r*(sWh[2]+hb2));
      float hn = (1.f-z)*n + z*hp;
      uc_stf(&hseq[(size_t)t*H + i], hn);
      shc[w] = hn;
    }
    __syncthreads();           // drain h stores; shc ready
    if(tid==0) bump(cnt, CH_EH, b);   // h visible BEFORE atomics finish

    // ---- logits partials via atomics ----
    if(tid < 257){
      float s = 0.f;
      #pragma unroll
      for(int w2=0; w2<WPB; w2++)
        s += scT[w2*ACC_N + tid] * shc[w2];
      atomicAdd(&accA[(b & (ACC_ROWS-1))*ACC_N + tid],
                (unsigned long long)(long long)rintf(s*SCALEF));
    }
    __syncthreads();           // drain atomics
    if(tid==0) bump(cnt, CH_EA, b);
  }

  // ================= epilogue: all 128 logp rows + tokens (parallel) =========
  waitline(cnt, CH_EA, tid, (unsigned)(8*ML));
  __syncthreads();
  if(b < ML && w == 0){
    const unsigned long long* accC = accseq + (size_t)(b+1)*ACC_STEP;
    long long s0 = 0, s1 = 0;
    #pragma unroll
    for(int r2=0; r2<ACC_ROWS; r2++){
      s0 += ((const long long*)accC)[r2*ACC_N + MLP1 + lane];
      s1 += ((const long long*)accC)[r2*ACC_N + MLP1 + 64 + lane];
    }
    float o0 = (float)((double)s0 * INV_SCALED) + ob0;
    float o1 = (float)((double)s1 * INV_SCALED) + ob1;
    float mv; int mi;
    if(o0 >= o1){ mv=o0; mi=lane; } else { mv=o1; mi=64+lane; }
    #pragma unroll
    for(int sft=32; sft>0; sft>>=1){
      float ov = __shfl_xor(mv, sft, 64);
      int   oi = __shfl_xor(mi, sft, 64);
      if(ov > mv || (ov == mv && oi < mi)){ mv = ov; mi = oi; }
    }
    float e0 = expf(o0-mv) + expf(o1-mv);
    float ss = wred(e0);
    float lse = mv + logf(ss);
    out[(size_t)b*V + lane]      = o0 - lse;
    out[(size_t)b*V + 64 + lane] = o1 - lse;
    if(lane==0) out[(size_t)ML*V + b] = (float)mi;
  }
}

extern "C" void kernel_launch(void* const* d_in, const int* in_sizes, int n_in,
                              void* d_out, int out_size, void* d_ws, size_t ws_size,
                              hipStream_t stream){
  (void)in_sizes; (void)n_in; (void)out_size; (void)ws_size;
  const int*   toks    = (const int*)  d_in[0];
  // d_in[1] = max_length (compile-time 128)
  const float* emb_enc = (const float*)d_in[2];
  const float* enc_Wih = (const float*)d_in[3];
  const float* enc_Whh = (const float*)d_in[4];
  const float* enc_bih = (const float*)d_in[5];
  const float* enc_bhh = (const float*)d_in[6];
  const float* emb_dec = (const float*)d_in[7];
  const float* attn_W  = (const float*)d_in[8];
  const float* attn_b  = (const float*)d_in[9];
  const float* comb_W  = (const float*)d_in[10];
  const float* comb_b  = (const float*)d_in[11];
  const float* dec_Wih = (const float*)d_in[12];
  const float* dec_Whh = (const float*)d_in[13];
  const float* dec_bih = (const float*)d_in[14];
  const float* dec_bhh = (const float*)d_in[15];
  const float* out_W   = (const float*)d_in[16];
  const float* out_b   = (const float*)d_in[17];
  float* outp = (float*)d_out;
  char*  ws   = (char*)d_ws;

  hipMemsetAsync(d_ws, 0, MEMSET_BYTES, stream);

  void* args[] = { &toks, &emb_enc, &enc_Wih, &enc_Whh, &enc_bih, &enc_bhh,
                   &emb_dec, &attn_W, &attn_b, &comb_W, &comb_b,
                   &dec_Wih, &dec_Whh, &dec_bih, &dec_bhh, &out_W, &out_b,
                   &outp, &ws };
  hipLaunchCooperativeKernel((void*)seq2seq_kernel, dim3(NBLK), dim3(NTHR),
                             args, 0, stream);
}

// Round 6
// 1926.258 us; speedup vs baseline: 1.1187x; 1.1187x over previous
//
#include <hip/hip_runtime.h>
#include <math.h>

#define H     1536
#define H3    4608
#define V     128
#define ML    128
#define MLP1  129
#define LEN   64
#define NBLK  256
#define NTHR  384          // 6 waves
#define WPB   6
#define NWAVE (NBLK*WPB)   // 1536
#define ACC_N    260       // padded 257 (129 attn + 128 out logits)
#define ACC_ROWS 8
#define ACC_STEP (ACC_ROWS*ACC_N)   // 2080 ull per step
#define TA_STRIDE 132

#define SCALEF     1099511627776.0f            // 2^40
#define INV_SCALED 9.094947017729282379150390625e-13  // 2^-40 (double, exact)

// epoch channels
#define CH_ENC 0
#define CH_EX  1
#define CH_EH  2
#define CH_EA  3

// ---- workspace layout (bytes) ----
// write-once-per-address discipline: writers use UC stores / atomics,
// readers use plain cached loads (first touch is post-publish/detect).
#define OFF_BAR 0                         // 4096: setup barrier lines
#define OFF_CNT 4096                      // 4096: 4 ch x 16 lines x 64B epochs
#define OFF_ACC 8192                      // ull[129][8][260] = 2146560
#define MEMSET_BYTES 2154752              // bar + cnt + accseq
#define OFF_HS  2154752                   // float[128][1536] decoder h seq
#define OFF_XS  2941184                   // float[128][1536] decoder x seq
#define OFF_XE  3727616                   // float[64][1536]
#define OFF_GI  4120832                   // float[64][4608]
#define OFF_EO  5300480                   // float[64][1536]
#define OFF_M   5693696                   // float[1536][64]
#define OFF_TA  6086912                   // float[128][132]
#define OFF_TC  6154496                   // float[128][1536]
#define OFF_CT  6940928                   // float[1536][260]
#define WS_END  8538368

// ---- cache-bypassing (device-coherent) accessors ----
__device__ __forceinline__ void uc_stf(float* p, float v){
  __hip_atomic_store(p, v, __ATOMIC_RELAXED, __HIP_MEMORY_SCOPE_AGENT);
}
__device__ __forceinline__ unsigned uc_ldu(const unsigned* p){
  return __hip_atomic_load(p, __ATOMIC_RELAXED, __HIP_MEMORY_SCOPE_AGENT);
}
__device__ __forceinline__ void uc_stu64(unsigned long long* p, unsigned long long v){
  __hip_atomic_store(p, v, __ATOMIC_RELAXED, __HIP_MEMORY_SCOPE_AGENT);
}

// ---- epoch primitives: producer-count, consumer-detect ----------------------
// 16 lines per channel (64B apart); block b bumps line b>>4; consumers use 16
// threads, each watching one line, until it reaches target = 16*epoch.
__device__ __forceinline__ void bump(unsigned* cnt, int ch, int b){
  __hip_atomic_fetch_add(cnt + (ch*16 + (b>>4))*16, 1u,
                         __ATOMIC_RELAXED, __HIP_MEMORY_SCOPE_AGENT);
}
__device__ __forceinline__ void waitline(const unsigned* cnt, int ch, int tid,
                                         unsigned target){
  if(tid < 16){
    const unsigned* line = cnt + (ch*16 + tid)*16;
    while(uc_ldu(line) < target) __builtin_amdgcn_s_sleep(1);
  }
}

__device__ __forceinline__ float wred(float v){
  #pragma unroll
  for(int s=32;s>0;s>>=1) v += __shfl_xor(v, s, 64);
  return v;
}

__device__ __forceinline__ void load6(const float* p, int lane, float4 r[6]){
  const float4* q = (const float4*)p;
  #pragma unroll
  for(int c=0;c<6;c++) r[c] = q[c*64+lane];
}
__device__ __forceinline__ float dot4(const float4 a, const float4 b){
  return a.x*b.x + a.y*b.y + a.z*b.z + a.w*b.w;
}
__device__ __forceinline__ float dot6(const float4 a[6], const float4 b[6]){
  float s=0.f;
  #pragma unroll
  for(int c=0;c<6;c++) s += dot4(a[c], b[c]);
  return s;
}

// ---- monotonic two-level tree barrier (setup phases only, 4 rounds) --------
__device__ __forceinline__ void gbar(unsigned* bar, int rnd){
  __syncthreads();
  if(threadIdx.x==0){
    unsigned* grp  = bar + 32*(1 + (blockIdx.x >> 4));
    unsigned* root = bar;
    unsigned a = __hip_atomic_fetch_add(grp, 1u, __ATOMIC_RELAXED, __HIP_MEMORY_SCOPE_AGENT);
    if((a & 0xFFFFu) == (unsigned)(16*rnd + 15)){
      unsigned ra = __hip_atomic_fetch_add(root, 1u, __ATOMIC_RELAXED, __HIP_MEMORY_SCOPE_AGENT);
      if(ra == (unsigned)(16*rnd + 15)){
        #pragma unroll
        for(int g=0; g<16; g++)
          __hip_atomic_fetch_add(bar + 32*(1+g), 0x10000u,
                                 __ATOMIC_RELAXED, __HIP_MEMORY_SCOPE_AGENT);
      } else {
        while((uc_ldu(grp) >> 16) < (unsigned)(rnd+1))
          __builtin_amdgcn_s_sleep(1);
      }
    } else {
      while((uc_ldu(grp) >> 16) < (unsigned)(rnd+1))
        __builtin_amdgcn_s_sleep(1);
    }
  }
  __syncthreads();
}

__global__ __launch_bounds__(NTHR, 2)
void seq2seq_kernel(const int* __restrict__ toks,
                    const float* __restrict__ emb_enc,
                    const float* __restrict__ enc_Wih,
                    const float* __restrict__ enc_Whh,
                    const float* __restrict__ enc_bih,
                    const float* __restrict__ enc_bhh,
                    const float* __restrict__ emb_dec,
                    const float* __restrict__ attn_W,
                    const float* __restrict__ attn_b,
                    const float* __restrict__ comb_W,
                    const float* __restrict__ comb_b,
                    const float* __restrict__ dec_Wih,
                    const float* __restrict__ dec_Whh,
                    const float* __restrict__ dec_bih,
                    const float* __restrict__ dec_bhh,
                    const float* __restrict__ out_W,
                    const float* __restrict__ out_b,
                    float* __restrict__ out,
                    char* __restrict__ ws)
{
  const int tid = threadIdx.x, b = blockIdx.x;
  const int lane = tid & 63, w = tid >> 6;
  const int gw = b*WPB + w;          // 0..1535
  int rnd = 0;

  unsigned* bar = (unsigned*)ws;
  unsigned* cnt = (unsigned*)(ws + OFF_CNT);
  unsigned long long* accseq = (unsigned long long*)(ws + OFF_ACC);
  float* hseq = (float*)(ws + OFF_HS);
  float* xseq = (float*)(ws + OFF_XS);
  float* Xe = (float*)(ws + OFF_XE);
  float* Gi = (float*)(ws + OFF_GI);
  float* EO = (float*)(ws + OFF_EO);
  float* Mm = (float*)(ws + OFF_M);
  float* tA = (float*)(ws + OFF_TA);
  float* tC = (float*)(ws + OFF_TC);
  float* cT = (float*)(ws + OFF_CT);

  __shared__ float smem[WPB*3*H];    // 110.6 KB: Whh pin / GEMM tiles
  __shared__ float sh[H];            // staged h (6 KB)
  __shared__ float sx[H];            // staged x (6 KB)
  __shared__ float scT[WPB*ACC_N];   // block's 6 cT rows (6.25 KB)
  __shared__ float sv[ACC_N];
  __shared__ float shc[8];

  // ================= E0: gather encoder inputs X, build colT (UC writes) =====
  for(int idx = b*NTHR + tid; idx < LEN*H; idx += NBLK*NTHR){
    int t = idx / H, k = idx - t*H;
    uc_stf(&Xe[idx], emb_enc[toks[t]*H + k]);
  }
  for(int idx = b*NTHR + tid; idx < H*257; idx += NBLK*NTHR){
    int i = idx / 257, c = idx - i*257;
    float v = (c < MLP1) ? attn_W[(size_t)c*2*H + H + i]
                         : out_W[(size_t)(c-MLP1)*H + i];
    uc_stf(&cT[(size_t)i*ACC_N + c], v);
  }
  gbar(bar, rnd++);

  // ================= E1: Gi = enc_Wih @ X^T + bih (tiled GEMM) ================
  {
    int r = b*18 + w*3;
    for(int g=0; g<4; g++){
      __syncthreads();
      for(int idx = tid; idx < 16*384; idx += NTHR)
        ((float4*)smem)[idx] = ((const float4*)Xe)[g*16*384 + idx];
      __syncthreads();
      float4 rv0[6], rv1[6], rv2[6];
      load6(enc_Wih + (size_t)r*H,     lane, rv0);
      load6(enc_Wih + (size_t)(r+1)*H, lane, rv1);
      load6(enc_Wih + (size_t)(r+2)*H, lane, rv2);
      float a0[16], a1[16], a2[16];
      #pragma unroll
      for(int t2=0;t2<16;t2++){ a0[t2]=0.f; a1[t2]=0.f; a2[t2]=0.f; }
      #pragma unroll
      for(int c=0;c<6;c++){
        #pragma unroll
        for(int t2=0;t2<16;t2++){
          float4 x = ((float4*)smem)[t2*384 + c*64 + lane];
          a0[t2] += dot4(rv0[c], x);
          a1[t2] += dot4(rv1[c], x);
          a2[t2] += dot4(rv2[c], x);
        }
      }
      float bi0 = enc_bih[r], bi1 = enc_bih[r+1], bi2 = enc_bih[r+2];
      #pragma unroll
      for(int t2=0;t2<16;t2++){
        float s0 = wred(a0[t2]), s1 = wred(a1[t2]), s2 = wred(a2[t2]);
        if(lane==0){
          uc_stf(&Gi[(size_t)(g*16+t2)*H3 + r    ], s0 + bi0);
          uc_stf(&Gi[(size_t)(g*16+t2)*H3 + r + 1], s1 + bi1);
          uc_stf(&Gi[(size_t)(g*16+t2)*H3 + r + 2], s2 + bi2);
        }
      }
    }
  }
  gbar(bar, rnd++);

  // ================= TC: tblCT[v][i] = comb_W[i][:H] . emb_dec[v] ============
  {
    int i = gw;
    float4 rv[6]; load6(comb_W + (size_t)i*2*H, lane, rv);
    for(int g=0; g<8; g++){
      __syncthreads();
      for(int idx = tid; idx < 16*384; idx += NTHR)
        ((float4*)smem)[idx] = ((const float4*)emb_dec)[g*16*384 + idx];
      __syncthreads();
      float a0[16];
      #pragma unroll
      for(int t2=0;t2<16;t2++) a0[t2]=0.f;
      #pragma unroll
      for(int c=0;c<6;c++){
        #pragma unroll
        for(int t2=0;t2<16;t2++){
          float4 x = ((float4*)smem)[t2*384 + c*64 + lane];
          a0[t2] += dot4(rv[c], x);
        }
      }
      #pragma unroll
      for(int t2=0;t2<16;t2++){
        float s = wred(a0[t2]);
        if(lane==0) uc_stf(&tC[(size_t)(g*16+t2)*H + i], s);
      }
    }
  }

  // ================= TA: tblAT[v][j] = attn_W[j][:H] . emb_dec[v] ============
  for(int task = gw; task < MLP1*V; task += NWAVE){
    int j = task >> 7, v = task & 127;
    float4 av[6]; load6(attn_W + (size_t)j*2*H, lane, av);
    float4 ev[6]; load6(emb_dec + (size_t)v*H, lane, ev);
    float s = wred(dot6(av, ev));
    if(lane==0) uc_stf(&tA[v*TA_STRIDE + j], s);
  }
  gbar(bar, rnd++);

  // ======= pin enc_Whh rows (i, i+H, i+2H for this block's 6 i's) in LDS =====
  for(int idx = tid; idx < 18*384; idx += NTHR){
    int row = idx/384, k4 = idx - row*384;
    int w2 = row/3, gate = row - w2*3;
    ((float4*)smem)[idx] =
      ((const float4*)enc_Whh)[((size_t)gate*H + b*WPB + w2)*384 + k4];
  }
  // ---- hoist encoder per-step constants into registers ----
  const int i0 = gw;
  float gi0 = Gi[(size_t)lane*H3 + i0];
  float gi1 = Gi[(size_t)lane*H3 + i0 + H];
  float gi2 = Gi[(size_t)lane*H3 + i0 + 2*H];
  float eb0 = enc_bhh[i0], eb1 = enc_bhh[i0+H], eb2 = enc_bhh[i0+2*H];
  __syncthreads();

  // ================= encoder loop: 64 steps, epoch handoff per step ==========
  for(int t=0; t<LEN; t++){
    if(t==0){
      float4 z4 = {0.f,0.f,0.f,0.f};
      ((float4*)sh)[tid] = z4;
    } else {
      waitline(cnt, CH_ENC, tid, (unsigned)(16*t));
      __syncthreads();
      ((float4*)sh)[tid] = ((const float4*)(EO + (size_t)(t-1)*H))[tid];
    }
    __syncthreads();
    float4 hv[6]; load6(sh, lane, hv);
    const float hp = sh[i0];
    float s[3];
    #pragma unroll
    for(int g=0; g<3; g++){
      const float4* sr = (const float4*)smem + (w*3+g)*384;
      float t0=0.f;
      #pragma unroll
      for(int c=0;c<6;c++) t0 += dot4(sr[c*64+lane], hv[c]);
      s[g] = wred(t0);
    }
    float ir = __shfl(gi0, t, 64), iz = __shfl(gi1, t, 64), in_ = __shfl(gi2, t, 64);
    if(lane==0){
      float r = 1.f/(1.f+expf(-(ir + s[0] + eb0)));
      float z = 1.f/(1.f+expf(-(iz + s[1] + eb1)));
      float n = tanhf(in_ + r*(s[2] + eb2));
      float hn = (1.f-z)*n + z*hp;
      uc_stf(&EO[(size_t)t*H + i0], hn);
    }
    __syncthreads();           // drains the EO stores of all waves
    if(tid==0) bump(cnt, CH_ENC, b);
  }
  waitline(cnt, CH_ENC, tid, (unsigned)(16*LEN));
  __syncthreads();             // all EO published

  // ================= M[i][j] = comb_W[i][H:] . enc_out[j] (j<64) =============
  {
    int i = gw;
    float4 rv[6]; load6(comb_W + (size_t)i*2*H + H, lane, rv);
    for(int g=0; g<4; g++){
      __syncthreads();
      for(int idx = tid; idx < 16*384; idx += NTHR)
        ((float4*)smem)[idx] = ((const float4*)EO)[g*16*384 + idx];
      __syncthreads();
      float a0[16];
      #pragma unroll
      for(int t2=0;t2<16;t2++) a0[t2]=0.f;
      #pragma unroll
      for(int c=0;c<6;c++){
        #pragma unroll
        for(int t2=0;t2<16;t2++){
          float4 x = ((float4*)smem)[t2*384 + c*64 + lane];
          a0[t2] += dot4(rv[c], x);
        }
      }
      #pragma unroll
      for(int t2=0;t2<16;t2++){
        float s = wred(a0[t2]);
        if(lane==0) uc_stf(&Mm[(size_t)i*64 + g*16 + t2], s);
      }
    }
  }

  // ====== a0: initial attn logits (raw h-part) into accseq[0] row 0 ==========
  if(gw < MLP1){
    int j = gw;
    float4 av[6]; load6(attn_W + (size_t)j*2*H + H, lane, av);
    float4 hv[6]; load6(EO + (size_t)(LEN-1)*H, lane, hv);  // final enc h
    float s = wred(dot6(av, hv));
    if(lane==0)
      uc_stu64(&accseq[j], (unsigned long long)(long long)rintf(s*SCALEF));
  }
  // pin dec_Whh rows in LDS
  for(int idx = tid; idx < 18*384; idx += NTHR){
    int row = idx/384, k4 = idx - row*384;
    int w2 = row/3, gate = row - w2*3;
    ((float4*)smem)[idx] =
      ((const float4*)dec_Whh)[((size_t)gate*H + b*WPB + w2)*384 + k4];
  }
  // block's 6 cT rows into LDS
  for(int idx = tid; idx < WPB*ACC_N; idx += NTHR){
    int w2 = idx / ACC_N, c = idx - w2*ACC_N;
    scT[idx] = cT[(size_t)(b*WPB + w2)*ACC_N + c];
  }
  gbar(bar, rnd++);

  // ---- hoist decoder per-step constants into registers (persistent) ----
  const int i = gw;
  float4 wx0[6], wx1[6], wx2[6];              // 72 VGPRs: this wave's Wx rows
  load6(dec_Wih + (size_t)i*H,         lane, wx0);
  load6(dec_Wih + ((size_t)H + i)*H,   lane, wx1);
  load6(dec_Wih + ((size_t)2*H + i)*H, lane, wx2);
  const float mreg = Mm[(size_t)i*64 + lane]; // Mm row, 1 float/lane
  const float ct0 = tC[(size_t)lane*H + i];   // tC column, 2 floats/lane
  const float ct1 = tC[(size_t)(64+lane)*H + i];
  const float ib0 = dec_bih[i], ib1 = dec_bih[i+H], ib2 = dec_bih[i+2*H];
  const float hb0 = dec_bhh[i], hb1 = dec_bhh[i+H], hb2 = dec_bhh[i+2*H];
  const float cb  = comb_b[i];
  const float ob0 = out_b[lane], ob1 = out_b[64+lane];
  const float ab0 = attn_b[lane], ab1 = attn_b[64+lane], ab2 = attn_b[128];

  // ================= decoder loop: 128 steps, 3 epoch handoffs each ==========
  // Schedule: [EH wait | stage sh (LLC read overlaps EA poll) | EA wait] ->
  // sv -> argmax/softmax -> publish x -> bump EX -> Wh.h (hides EX hop) ->
  // wait EX -> stage sx -> Wx.x -> gates -> publish h -> atomics.
  for(int t=0; t<ML; t++){
    const unsigned long long* accC = accseq + (size_t)t*ACC_STEP;
    unsigned long long* accA = accseq + (size_t)(t+1)*ACC_STEP;

    // ---- wait h(t-1); stage into LDS; EA poll overlaps the stage read ----
    if(t==0){
      ((float4*)sh)[tid] = ((const float4*)(EO + (size_t)(LEN-1)*H))[tid];
    } else {
      waitline(cnt, CH_EH, tid, (unsigned)(16*t));
      __syncthreads();
      ((float4*)sh)[tid] = ((const float4*)(hseq + (size_t)(t-1)*H))[tid];
      waitline(cnt, CH_EA, tid, (unsigned)(16*t));
    }
    __syncthreads();           // sh staged + acc(t) complete

    // ---- read acc partials into sv (257 threads, coalesced) ----
    if(tid < 257){
      long long s = 0;
      #pragma unroll
      for(int r2=0; r2<ACC_ROWS; r2++)
        s += ((const long long*)accC)[r2*ACC_N + tid];
      sv[tid] = (float)((double)s * INV_SCALED);
    }
    __syncthreads();

    // ---- per-wave register-only argmax over out logits (all waves) ----
    float o0 = sv[MLP1+lane]    + ob0;
    float o1 = sv[MLP1+64+lane] + ob1;
    float mv; int mi;
    if(o0 >= o1){ mv=o0; mi=lane; } else { mv=o1; mi=64+lane; }
    #pragma unroll
    for(int sft=32; sft>0; sft>>=1){
      float ov = __shfl_xor(mv, sft, 64);
      int   oi = __shfl_xor(mi, sft, 64);
      if(ov > mv || (ov == mv && oi < mi)){ mv = ov; mi = oi; }
    }
    const int tok = (t==0) ? 0 : mi;

    // ---- per-wave register-only attention softmax ----
    float v0 = sv[lane]      + tA[tok*TA_STRIDE + lane]      + ab0;
    float v1 = sv[64+lane]   + tA[tok*TA_STRIDE + 64 + lane] + ab1;
    float v2 = (lane==0) ? (sv[128] + tA[tok*TA_STRIDE + 128] + ab2) : -1e30f;
    float m0 = fmaxf(fmaxf(v0, v1), v2);
    #pragma unroll
    for(int sft=32; sft>0; sft>>=1) m0 = fmaxf(m0, __shfl_xor(m0, sft, 64));
    float e0 = expf(v0 - m0);
    float esum = e0 + expf(v1 - m0) + ((lane==0) ? expf(v2 - m0) : 0.f);
    esum = wred(esum);
    const float invd = 1.f/esum;

    // ---- x[i] = relu(tC[tok][i] + (Mm[i,:64].e)*invd + comb_b[i]); publish --
    {
      float s = wred(mreg * e0);
      float ctv = (tok < 64) ? __shfl(ct0, tok, 64) : __shfl(ct1, tok-64, 64);
      if(lane==0)
        uc_stf(&xseq[(size_t)t*H + i], fmaxf(ctv + s*invd + cb, 0.f));
    }
    __syncthreads();           // drain x stores
    if(tid==0) bump(cnt, CH_EX, b);

    // ---- Wh . h HERE: pure LDS compute, hides the EX propagation window ----
    float4 hv[6]; load6(sh, lane, hv);
    const float hp = sh[i];
    float sWh[3];
    #pragma unroll
    for(int g=0; g<3; g++){
      const float4* sp = (const float4*)smem + (w*3+g)*384;
      float t1=0.f;
      #pragma unroll
      for(int c=0;c<6;c++) t1 += dot4(sp[c*64+lane], hv[c]);
      sWh[g] = wred(t1);
    }

    // ---- wait x complete; stage; Wx . x; gates; publish h ----
    waitline(cnt, CH_EX, tid, (unsigned)(16*(t+1)));
    __syncthreads();
    ((float4*)sx)[tid] = ((const float4*)(xseq + (size_t)t*H))[tid];
    __syncthreads();
    float4 xv[6]; load6(sx, lane, xv);
    float t0=0.f, t1=0.f, t2=0.f;
    #pragma unroll
    for(int c=0;c<6;c++){
      t0 += dot4(wx0[c], xv[c]);
      t1 += dot4(wx1[c], xv[c]);
      t2 += dot4(wx2[c], xv[c]);
    }
    float sWx0 = wred(t0), sWx1 = wred(t1), sWx2 = wred(t2);
    if(lane==0){
      float r = 1.f/(1.f+expf(-(sWx0+ib0 + sWh[0]+hb0)));
      float z = 1.f/(1.f+expf(-(sWx1+ib1 + sWh[1]+hb1)));
      float n = tanhf(sWx2+ib2 + r*(sWh[2]+hb2));
      float hn = (1.f-z)*n + z*hp;
      uc_stf(&hseq[(size_t)t*H + i], hn);
      shc[w] = hn;
    }
    __syncthreads();           // drain h stores; shc ready
    if(tid==0) bump(cnt, CH_EH, b);   // h visible BEFORE atomics finish

    // ---- logits partials via atomics ----
    if(tid < 257){
      float s = 0.f;
      #pragma unroll
      for(int w2=0; w2<WPB; w2++)
        s += scT[w2*ACC_N + tid] * shc[w2];
      atomicAdd(&accA[(b & (ACC_ROWS-1))*ACC_N + tid],
                (unsigned long long)(long long)rintf(s*SCALEF));
    }
    __syncthreads();           // drain atomics
    if(tid==0) bump(cnt, CH_EA, b);
  }

  // ================= epilogue: all 128 logp rows + tokens (parallel) =========
  waitline(cnt, CH_EA, tid, (unsigned)(16*ML));
  __syncthreads();
  if(b < ML && w == 0){
    const unsigned long long* accC = accseq + (size_t)(b+1)*ACC_STEP;
    long long s0 = 0, s1 = 0;
    #pragma unroll
    for(int r2=0; r2<ACC_ROWS; r2++){
      s0 += ((const long long*)accC)[r2*ACC_N + MLP1 + lane];
      s1 += ((const long long*)accC)[r2*ACC_N + MLP1 + 64 + lane];
    }
    float o0 = (float)((double)s0 * INV_SCALED) + ob0;
    float o1 = (float)((double)s1 * INV_SCALED) + ob1;
    float mv; int mi;
    if(o0 >= o1){ mv=o0; mi=lane; } else { mv=o1; mi=64+lane; }
    #pragma unroll
    for(int sft=32; sft>0; sft>>=1){
      float ov = __shfl_xor(mv, sft, 64);
      int   oi = __shfl_xor(mi, sft, 64);
      if(ov > mv || (ov == mv && oi < mi)){ mv = ov; mi = oi; }
    }
    float e0 = expf(o0-mv) + expf(o1-mv);
    float ss = wred(e0);
    float lse = mv + logf(ss);
    out[(size_t)b*V + lane]      = o0 - lse;
    out[(size_t)b*V + 64 + lane] = o1 - lse;
    if(lane==0) out[(size_t)ML*V + b] = (float)mi;
  }
}

extern "C" void kernel_launch(void* const* d_in, const int* in_sizes, int n_in,
                              void* d_out, int out_size, void* d_ws, size_t ws_size,
                              hipStream_t stream){
  (void)in_sizes; (void)n_in; (void)out_size; (void)ws_size;
  const int*   toks    = (const int*)  d_in[0];
  // d_in[1] = max_length (compile-time 128)
  const float* emb_enc = (const float*)d_in[2];
  const float* enc_Wih = (const float*)d_in[3];
  const float* enc_Whh = (const float*)d_in[4];
  const float* enc_bih = (const float*)d_in[5];
  const float* enc_bhh = (const float*)d_in[6];
  const float* emb_dec = (const float*)d_in[7];
  const float* attn_W  = (const float*)d_in[8];
  const float* attn_b  = (const float*)d_in[9];
  const float* comb_W  = (const float*)d_in[10];
  const float* comb_b  = (const float*)d_in[11];
  const float* dec_Wih = (const float*)d_in[12];
  const float* dec_Whh = (const float*)d_in[13];
  const float* dec_bih = (const float*)d_in[14];
  const float* dec_bhh = (const float*)d_in[15];
  const float* out_W   = (const float*)d_in[16];
  const float* out_b   = (const float*)d_in[17];
  float* outp = (float*)d_out;
  char*  ws   = (char*)d_ws;

  hipMemsetAsync(d_ws, 0, MEMSET_BYTES, stream);

  void* args[] = { &toks, &emb_enc, &enc_Wih, &enc_Whh, &enc_bih, &enc_bhh,
                   &emb_dec, &attn_W, &attn_b, &comb_W, &comb_b,
                   &dec_Wih, &dec_Whh, &dec_bih, &dec_bhh, &out_W, &out_b,
                   &outp, &ws };
  hipLaunchCooperativeKernel((void*)seq2seq_kernel, dim3(NBLK), dim3(NTHR),
                             args, 0, stream);
}